// Round 3
// baseline (432.035 us; speedup 1.0000x reference)
//
#include <hip/hip_runtime.h>
#include <math.h>

// GraphAttention single-node aggregate, restructured:
//   w = kernel @ attn_neigh            (128)   -- prep kernel
//   x_t = x @ kernel                   (64)    -- prep kernel
//   s_i = X_i . w ; online softmax over N; acc = sum p_i * X_i (128)  -- main
//   out = 0.75 * ((acc/L) @ kernel) + 0.25 * x_t                      -- finalize
// attn_self drops out entirely (softmax shift invariance).
//
// R3 changes (latency-bound theory): unconditional loads (no per-iter tail
// guard), 2x unrolled loop with two independent softmax states (2 loads in
// flight per wave), 1024 blocks for ~24+ waves/CU. Odd-N tail handled once.

#define TPB 512          // 8 waves per block in main kernel
#define MAXBLK 1024      // partial-buffer blocks
#define PART_STRIDE 136  // floats per block partial: [0]=m,[1]=l,[8..135]=acc
#define PART_BASE 256    // float offset in ws where partials start (0..127=w, 128..191=x_t)

__global__ __launch_bounds__(128) void gat_prep(
    const float* __restrict__ x, const float* __restrict__ kern,
    const float* __restrict__ attn_neigh, float* __restrict__ ws) {
  int t = threadIdx.x;  // 128 threads
  float s = 0.f;
#pragma unroll 8
  for (int c = 0; c < 64; ++c) s += kern[t * 64 + c] * attn_neigh[c];
  ws[t] = s;
  if (t < 64) {
    float s2 = 0.f;
#pragma unroll 8
    for (int j = 0; j < 128; ++j) s2 += x[j] * kern[j * 64 + t];
    ws[128 + t] = s2;
  }
}

__global__ __launch_bounds__(TPB, 6) void gat_main(
    const float4* __restrict__ X4, const float* __restrict__ ws,
    float* __restrict__ part, int N, int totalWaves) {
  const int lane = threadIdx.x & 63;
  const int half = lane >> 5;       // 0: even row of pair, 1: odd row
  const int hl = lane & 31;
  const int wid = threadIdx.x >> 6; // wave in block (0..7)
  const int gwave = blockIdx.x * (TPB / 64) + wid;

  const float4 wv = ((const float4*)ws)[hl];  // w fragment: features 4*hl..4*hl+3

  const int npairs = N >> 1;  // full pairs; odd row handled after the loop

  // Two independent online-softmax states (A: even-strided chunks, B: odd).
  float mA = -INFINITY, lA = 0.f, aAx = 0.f, aAy = 0.f, aAz = 0.f, aAw = 0.f;
  float mB = -INFINITY, lB = 0.f, aBx = 0.f, aBy = 0.f, aBz = 0.f, aBw = 0.f;

  int p = gwave;
  const int stride = totalWaves;
  for (; p + stride < npairs; p += 2 * stride) {
    // issue both loads up front (independent, unconditional)
    const float4 xv0 = X4[(size_t)p * 64 + lane];
    const float4 xv1 = X4[(size_t)(p + stride) * 64 + lane];

    float s0 = xv0.x * wv.x + xv0.y * wv.y + xv0.z * wv.z + xv0.w * wv.w;
    s0 += __shfl_xor(s0, 1);  s0 += __shfl_xor(s0, 2);  s0 += __shfl_xor(s0, 4);
    s0 += __shfl_xor(s0, 8);  s0 += __shfl_xor(s0, 16);
    {
      const float mn = fmaxf(mA, s0);
      const float corr = __expf(mA - mn);   // mA=-inf -> corr=0 (safe)
      const float pw = __expf(s0 - mn);
      lA = lA * corr + pw;
      aAx = aAx * corr + pw * xv0.x;  aAy = aAy * corr + pw * xv0.y;
      aAz = aAz * corr + pw * xv0.z;  aAw = aAw * corr + pw * xv0.w;
      mA = mn;
    }
    float s1 = xv1.x * wv.x + xv1.y * wv.y + xv1.z * wv.z + xv1.w * wv.w;
    s1 += __shfl_xor(s1, 1);  s1 += __shfl_xor(s1, 2);  s1 += __shfl_xor(s1, 4);
    s1 += __shfl_xor(s1, 8);  s1 += __shfl_xor(s1, 16);
    {
      const float mn = fmaxf(mB, s1);
      const float corr = __expf(mB - mn);
      const float pw = __expf(s1 - mn);
      lB = lB * corr + pw;
      aBx = aBx * corr + pw * xv1.x;  aBy = aBy * corr + pw * xv1.y;
      aBz = aBz * corr + pw * xv1.z;  aBw = aBw * corr + pw * xv1.w;
      mB = mn;
    }
  }
  if (p < npairs) {  // single leftover chunk -> state A
    const float4 xv0 = X4[(size_t)p * 64 + lane];
    float s0 = xv0.x * wv.x + xv0.y * wv.y + xv0.z * wv.z + xv0.w * wv.w;
    s0 += __shfl_xor(s0, 1);  s0 += __shfl_xor(s0, 2);  s0 += __shfl_xor(s0, 4);
    s0 += __shfl_xor(s0, 8);  s0 += __shfl_xor(s0, 16);
    const float mn = fmaxf(mA, s0);
    const float corr = __expf(mA - mn);
    const float pw = __expf(s0 - mn);
    lA = lA * corr + pw;
    aAx = aAx * corr + pw * xv0.x;  aAy = aAy * corr + pw * xv0.y;
    aAz = aAz * corr + pw * xv0.z;  aAw = aAw * corr + pw * xv0.w;
    mA = mn;
  }

  // odd-N tail: one extra row, handled by gwave 0's lower half once
  if ((N & 1) && gwave == 0) {
    float4 xv = make_float4(0.f, 0.f, 0.f, 0.f);
    if (half == 0) xv = X4[(size_t)(N - 1) * 32 + hl];
    float s = xv.x * wv.x + xv.y * wv.y + xv.z * wv.z + xv.w * wv.w;
    s += __shfl_xor(s, 1);  s += __shfl_xor(s, 2);  s += __shfl_xor(s, 4);
    s += __shfl_xor(s, 8);  s += __shfl_xor(s, 16);
    if (half == 0) {
      const float mn = fmaxf(mA, s);
      const float corr = __expf(mA - mn);
      const float pw = __expf(s - mn);
      lA = lA * corr + pw;
      aAx = aAx * corr + pw * xv.x;  aAy = aAy * corr + pw * xv.y;
      aAz = aAz * corr + pw * xv.z;  aAw = aAw * corr + pw * xv.w;
      mA = mn;
    }
  }

  // merge state B into state A (lane-local)
  float m, l, ax, ay, az, aw;
  {
    const float M = fmaxf(mA, mB);
    const float cA = (mA == -INFINITY) ? 0.f : __expf(mA - M);
    const float cB = (mB == -INFINITY) ? 0.f : __expf(mB - M);
    l = lA * cA + lB * cB;
    ax = aAx * cA + aBx * cB;  ay = aAy * cA + aBy * cB;
    az = aAz * cA + aBz * cB;  aw = aAw * cA + aBw * cB;
    m = M;
  }

  // combine the two 32-lane halves of this wave
  const float m_o = __shfl_xor(m, 32);
  const float l_o = __shfl_xor(l, 32);
  const float axo = __shfl_xor(ax, 32);
  const float ayo = __shfl_xor(ay, 32);
  const float azo = __shfl_xor(az, 32);
  const float awo = __shfl_xor(aw, 32);
  const float M2 = fmaxf(m, m_o);
  const float c0 = (m == -INFINITY) ? 0.f : __expf(m - M2);
  const float c1 = (m_o == -INFINITY) ? 0.f : __expf(m_o - M2);
  const float l2 = l * c0 + l_o * c1;
  const float bx = ax * c0 + axo * c1;
  const float by = ay * c0 + ayo * c1;
  const float bz = az * c0 + azo * c1;
  const float bw = aw * c0 + awo * c1;

  __shared__ float sm[TPB / 64];
  __shared__ float sl[TPB / 64];
  __shared__ float sacc[TPB / 64][128];
  if (lane < 32) {
    sacc[wid][hl * 4 + 0] = bx;
    sacc[wid][hl * 4 + 1] = by;
    sacc[wid][hl * 4 + 2] = bz;
    sacc[wid][hl * 4 + 3] = bw;
    if (hl == 0) { sm[wid] = M2; sl[wid] = l2; }
  }
  __syncthreads();

  if (threadIdx.x < 32) {
    float Mb = -INFINITY;
#pragma unroll
    for (int w2 = 0; w2 < TPB / 64; ++w2) Mb = fmaxf(Mb, sm[w2]);
    float Lb = 0.f, fx = 0.f, fy = 0.f, fz = 0.f, fw = 0.f;
#pragma unroll
    for (int w2 = 0; w2 < TPB / 64; ++w2) {
      const float sc = (sm[w2] == -INFINITY) ? 0.f : __expf(sm[w2] - Mb);
      Lb += sc * sl[w2];
      fx += sc * sacc[w2][hl * 4 + 0];
      fy += sc * sacc[w2][hl * 4 + 1];
      fz += sc * sacc[w2][hl * 4 + 2];
      fw += sc * sacc[w2][hl * 4 + 3];
    }
    float* pb = part + (size_t)blockIdx.x * PART_STRIDE;
    if (hl == 0) { pb[0] = Mb; pb[1] = Lb; }
    float4 v = make_float4(fx, fy, fz, fw);
    ((float4*)(pb + 8))[hl] = v;  // 16B-aligned: PART_BASE/STRIDE multiples of 8
  }
}

__global__ __launch_bounds__(256) void gat_fin(
    const float* __restrict__ kern, const float* __restrict__ ws,
    float* __restrict__ out, int nblk) {
  __shared__ float scale[MAXBLK];
  __shared__ float red[256];
  __shared__ float feats[128];
  const int t = threadIdx.x;  // 256 threads
  const float* part = ws + PART_BASE;

  // global max M over block partials
  float m = -INFINITY;
  for (int b = t; b < nblk; b += 256) m = fmaxf(m, part[(size_t)b * PART_STRIDE]);
  red[t] = m;
  __syncthreads();
  for (int s = 128; s > 0; s >>= 1) {
    if (t < s) red[t] = fmaxf(red[t], red[t + s]);
    __syncthreads();
  }
  const float M = red[0];
  __syncthreads();

  // scales + global L
  float lp = 0.f;
  for (int b = t; b < nblk; b += 256) {
    const float mb = part[(size_t)b * PART_STRIDE];
    const float sc = (mb == -INFINITY) ? 0.f : __expf(mb - M);
    scale[b] = sc;
    lp += sc * part[(size_t)b * PART_STRIDE + 1];
  }
  red[t] = lp;
  __syncthreads();
  for (int s = 128; s > 0; s >>= 1) {
    if (t < s) red[t] += red[t + s];
    __syncthreads();
  }
  const float L = red[0];
  __syncthreads();

  // feats[j] = (1/L) * sum_b scale_b * acc_b[j]   (attn @ X in 128-dim space)
  if (t < 128) {
    float f = 0.f;
    for (int b = 0; b < nblk; ++b) f += scale[b] * part[(size_t)b * PART_STRIDE + 8 + t];
    feats[t] = f / L;
  }
  __syncthreads();

  // out[c] = 0.75 * (feats @ kernel)[c] + 0.25 * x_t[c]
  if (t < 64) {
    float s = 0.f;
#pragma unroll 8
    for (int j = 0; j < 128; ++j) s += feats[j] * kern[j * 64 + t];
    out[t] = 0.75f * s + 0.25f * ws[128 + t];
  }
}

extern "C" void kernel_launch(void* const* d_in, const int* in_sizes, int n_in,
                              void* d_out, int out_size, void* d_ws, size_t ws_size,
                              hipStream_t stream) {
  const float* x          = (const float*)d_in[0];
  const float* X          = (const float*)d_in[1];
  const float* kern       = (const float*)d_in[2];
  // d_in[3] = attn_self: unused — softmax is invariant to the constant shift.
  const float* attn_neigh = (const float*)d_in[4];
  float* ws  = (float*)d_ws;
  float* out = (float*)d_out;

  const int N = in_sizes[1] / 128;

  // Guard: prep region + block partials must fit in ws (always true at 1 GB).
  int nblk = MAXBLK;
  const size_t availF = ws_size / 4;
  if (availF < (size_t)PART_BASE + (size_t)MAXBLK * PART_STRIDE) {
    long cap = ((long)availF - PART_BASE) / PART_STRIDE;
    nblk = (cap < 1) ? 1 : (int)cap;
  }
  const int totalWaves = nblk * (TPB / 64);

  gat_prep<<<1, 128, 0, stream>>>(x, kern, attn_neigh, ws);
  gat_main<<<nblk, TPB, 0, stream>>>((const float4*)X, ws, ws + PART_BASE,
                                     N, totalWaves);
  gat_fin<<<1, 256, 0, stream>>>(kern, ws, out, nblk);
}